// Round 13
// baseline (149.801 us; speedup 1.0000x reference)
//
#include <hip/hip_runtime.h>
#include <hip/hip_fp16.h>

typedef _Float16 h16;
typedef h16 v2h __attribute__((ext_vector_type(2)));
typedef h16 v4h __attribute__((ext_vector_type(4)));
typedef h16 v8h __attribute__((ext_vector_type(8)));
typedef float f4 __attribute__((ext_vector_type(4)));

#define NATOM 4096
#define HALF_N 2048
#define K2 2.885390081777927f      // 2/ln2: tanh(x) = 1 - 2/(1+exp2(K2*x))
#define GSCL 0.015625f             // G stored as fp16 * 1/64
#define W0SCL (64.0f * K2)         // W0t staged as fp16 * 64 * K2
#define USCL 0.0625f               // U rows stored /16 (fp16 headroom)
#define GOUTS (GSCL / USCL)        // 0.25: G16 = (U/16 · V) * 0.25 = G/64

// ---- embedding table: E(srcn) tabulated on w = s/(8+|s|), uniform in w ----
#define TBL_N 2048
#define W0MIN_ (-0.201f)
#define DW_ (1.2005f / 2047.0f)
#define RSCALE_ (2047.0f / 1.2005f)

__device__ __forceinline__ float rcp_fast(float x) {
#if __has_builtin(__builtin_amdgcn_rcpf)
  return __builtin_amdgcn_rcpf(x);
#else
  return 1.0f / x;
#endif
}

__device__ __forceinline__ float exp2_fast(float x) {
#if __has_builtin(__builtin_amdgcn_exp2f)
  return __builtin_amdgcn_exp2f(x);
#else
  return exp2f(x);
#endif
}

// input d is already pre-scaled by K2=2/ln2: returns tanh(d/K2)
__device__ __forceinline__ float tanh_e2(float d) {
  float r = rcp_fast(1.0f + exp2_fast(d));
  return fmaf(-2.0f, r, 1.0f);
}

__device__ __forceinline__ v8h lds_v8h(const h16* base, int byte) {
  return *(const v8h*)((const char*)base + byte);
}

// ---------------------------------------------------------------------------
// Setup. Blocks 0..511: embedding table. 512..639: fW0 -> W0t transpose.
// 640..655: coord float4 pack. 656..671: fW1 -> W1t transpose.
// ---------------------------------------------------------------------------
__global__ __launch_bounds__(256) void k_setup(
    const float* __restrict__ eW0, const float* __restrict__ eb0,
    const float* __restrict__ eW1, const float* __restrict__ eb1,
    const float* __restrict__ eW2, const float* __restrict__ eb2,
    const float* __restrict__ fW0, const float* __restrict__ fW1,
    const float* __restrict__ coord,
    h16* __restrict__ tbl, h16* __restrict__ W0t, h16* __restrict__ W1t,
    f4* __restrict__ coordP)
{
  const int bid = blockIdx.x, tid = threadIdx.x;
  if (bid < 512) {
    __shared__ float sW1[512];
    __shared__ float sW2[2048];
    __shared__ float sW0s[16], sb0s[16], sb1s[32], sb2s[64];
    const int net = bid >> 7;
    for (int i = tid; i < 512; i += 256) sW1[i] = eW1[net * 512 + i];
    for (int i = tid; i < 2048; i += 256) sW2[i] = eW2[net * 2048 + i];
    if (tid < 16) { sW0s[tid] = eW0[net * 16 + tid]; sb0s[tid] = eb0[net * 16 + tid]; }
    else if (tid >= 32 && tid < 64) sb1s[tid - 32] = eb1[net * 32 + tid - 32];
    else if (tid >= 64 && tid < 128) sb2s[tid - 64] = eb2[net * 64 + tid - 64];
    __syncthreads();

    const int u = (bid & 127) * 256 + tid;     // 0..32767
    const int e = u >> 4, cq = u & 15;
    const float w = W0MIN_ + (float)e * DW_;
    const float s = 8.0f * w * rcp_fast(1.0f - fabsf(w));
    float h0[16];
#pragma unroll
    for (int i = 0; i < 16; ++i)
      h0[i] = tanh_e2(K2 * fmaf(s, sW0s[i], sb0s[i]));
    float h1[32];
#pragma unroll
    for (int j = 0; j < 32; ++j) {
      float a = sb1s[j];
#pragma unroll
      for (int i = 0; i < 16; ++i) a = fmaf(h0[i], sW1[i * 32 + j], a);
      h1[j] = tanh_e2(K2 * a);
    }
    f4 a4 = *(const f4*)&sb2s[cq * 4];
    for (int j = 0; j < 32; ++j) {
      f4 wv4 = *(const f4*)&sW2[j * 64 + cq * 4];
      a4 += h1[j] * wv4;
    }
    union { h16 e4[4]; unsigned long long q; } o;
#pragma unroll
    for (int q = 0; q < 4; ++q) o.e4[q] = (h16)tanh_e2(K2 * a4[q]);
    *(unsigned long long*)&tbl[((size_t)(net * TBL_N + e)) * 64 + cq * 4] = o.q;
  } else if (bid < 640) {
    int idx = (bid - 512) * 256 + tid;          // 0..32767
    int t = idx >> 14, n = idx & 127, k8 = (idx >> 7) & 127;
    union { v8h v; h16 e[8]; } o;
#pragma unroll
    for (int i = 0; i < 8; ++i)
      o.e[i] = (h16)(W0SCL * fW0[(size_t)t * 131072 + (size_t)(k8 * 8 + i) * 128 + n]);
    *(v8h*)&W0t[((size_t)t * 128 + n) * 1024 + k8 * 8] = o.v;
  } else if (bid < 656) {
    int idx = (bid - 640) * 256 + tid;          // 0..4095
    f4 c;
    c.x = coord[idx]; c.y = coord[NATOM + idx]; c.z = coord[2 * NATOM + idx];
    c.w = 0.0f;
    coordP[idx] = c;
  } else {
    int idx = (bid - 656) * 256 + tid;          // 0..4095
    int t = idx >> 11, rem = idx & 2047;
    int n = rem >> 4, k8 = rem & 15;
    union { v8h v; h16 e[8]; } o;
#pragma unroll
    for (int i = 0; i < 8; ++i)
      o.e[i] = (h16)(K2 * fW1[(size_t)t * 16384 + (size_t)(k8 * 8 + i) * 128 + n]);
    *(v8h*)&W1t[((size_t)t * 128 + n) * 128 + k8 * 8] = o.v;
  }
}

// ---------------------------------------------------------------------------
// Kernel 1 (unchanged from round 12). MEASUREMENT ROUND: launched 11x to
// extract T_embed = (dur - 42.7)/10 from the total (idempotent: writes only
// G16, reads only setup outputs + inputs).
// ---------------------------------------------------------------------------
__global__ __launch_bounds__(256, 4) void k_embed(
    const f4* __restrict__ coordP, const float* __restrict__ box,
    const int* __restrict__ nbrs, const float* __restrict__ Tbias,
    const h16* __restrict__ tbl, h16* __restrict__ Gout)
{
  __shared__ h16 pool1[4][2560] __attribute__((aligned(16))); // E32t[64][40] / Vt[64][40]
  __shared__ h16 pool2[4][1360] __attribute__((aligned(16))); // Rls[10][136] / Uls[16][40]

  const int tid = threadIdx.x;
  const int wv = tid >> 6;
  const int lane = tid & 63;
  const int n = blockIdx.x * 4 + wv;
  const int ti = (n >= HALF_N) ? 1 : 0;
  const int c15 = lane & 15, g4 = lane >> 4;
  const int mp = lane >> 2, cg = lane & 3;   // gather mapping: m-pair x 16ch

  h16* E32 = &pool1[wv][0];   // [ch][40] during T phase; Vt [col][40] after
  h16* Rl  = &pool2[wv][0];   // [x][136] during T phase; Uls [a][40] after

  const int jnb0 = nbrs[(size_t)n * 128 + lane];
  const int jnb1 = nbrs[(size_t)n * 128 + 64 + lane];

  // ---- stage A: geometry + R rows + per-lane table index/frac regs ----
  int uf0 = 0, uf1 = 0;
  {
    const float bx = box[0], by = box[1], bz = box[2];
    const float rbx = rcp_fast(bx), rby = rcp_fast(by), rbz = rcp_fast(bz);
    const f4 cme = coordP[n];
#pragma unroll
    for (int nb = 0; nb < 2; ++nb) {
      const int m = nb * 64 + lane;
      const f4 cj = coordP[nb ? jnb1 : jnb0];
      float dx = cj.x - cme.x;
      float dy = cj.y - cme.y;
      float dz = cj.z - cme.z;
      dx -= bx * rintf(dx * rbx);
      dy -= by * rintf(dy * rby);
      dz -= bz * rintf(dz * rbz);
      float r2 = dx * dx + dy * dy + dz * dz;
      bool mk = r2 > 1e-12f;
      float rs = sqrtf(mk ? r2 : 1.0f);
      float r  = mk ? rs : 0.0f;
      float sw = 0.5f * __cosf(0.52359878f * fminf(r, 6.0f)) + 0.5f;
      float invr = mk ? rcp_fast(rs) : 1.0f;
      float sr = (mk && r < 6.0f) ? sw * invr : 0.0f;
      float x0 = dx * invr, x1 = dy * invr, x2 = dz * invr;
      float srn = sr * 20.0f;
      float s   = (sr - 0.1f) * 20.0f;
      Rl[0 * 136 + m] = (h16)srn;
      Rl[1 * 136 + m] = (h16)(1.7320508f * srn * x0);
      Rl[2 * 136 + m] = (h16)(1.7320508f * srn * x1);
      Rl[3 * 136 + m] = (h16)(1.7320508f * srn * x2);
      Rl[4 * 136 + m] = (h16)(3.0f * srn * (x0 * x0 - 0.33333334f));
      Rl[5 * 136 + m] = (h16)(3.0f * srn * (x1 * x1 - 0.33333334f));
      Rl[6 * 136 + m] = (h16)(3.0f * srn * (x2 * x2 - 0.33333334f));
      Rl[7 * 136 + m] = (h16)(4.2426407f * srn * (x0 * x1));
      Rl[8 * 136 + m] = (h16)(4.2426407f * srn * (x1 * x2));
      Rl[9 * 136 + m] = (h16)(4.2426407f * srn * (x2 * x0));
      float wr = s * rcp_fast(8.0f + fabsf(s));
      float fidx = (wr - W0MIN_) * RSCALE_;
      fidx = fminf(fmaxf(fidx, 0.0f), 2045.99f);
      float i0f = floorf(fidx);
      h16 frh = (h16)(fidx - i0f);
      int uf = ((int)i0f << 16) |
               (int)__builtin_bit_cast(unsigned short, frh);
      if (nb == 0) uf0 = uf; else uf1 = uf;
    }
  }

  union U8 { v8h v; v2h p[4]; h16 e[8]; };
  const int rrow = (c15 < 10) ? c15 : 9;
  const v8h vzero = {};
  f4 tac[4];
#pragma unroll
  for (int nt = 0; nt < 4; ++nt) tac[nt] = (f4){0.f, 0.f, 0.f, 0.f};

  // issue: gather chunk ks (2 m x 16 ch per lane) -> 8 v8h; returns 2 fracs
  auto issue = [&](int ks, U8* buf, float* fr) {
#pragma unroll
    for (int e = 0; e < 2; ++e) {
      int src = ((ks & 1) * 32 + mp * 2 + e) * 4;
      unsigned uu = (unsigned)__builtin_amdgcn_ds_bpermute(src, (ks < 2) ? uf0 : uf1);
      int i0 = (int)(uu >> 16);
      fr[e] = (float)__builtin_bit_cast(h16, (unsigned short)(uu & 0xffffu));
      const int net = ti * 2 + (ks >> 1);
      const h16* rp = tbl + ((size_t)net * TBL_N + i0) * 64 + cg * 16;
      buf[e * 4 + 0].v = *(const v8h*)(rp);            // row i0, ch 0..7
      buf[e * 4 + 1].v = *(const v8h*)(rp + 8);        // row i0, ch 8..15
      buf[e * 4 + 2].v = *(const v8h*)(rp + 64);       // row i0+1
      buf[e * 4 + 3].v = *(const v8h*)(rp + 72);
    }
  };

  // proc: lerp 2 m x 16 ch -> b32 transpose writes (LOCAL m), 4 T-MFMAs
  auto proc = [&](int ks, U8* buf, const float* fr) {
    v2h f0; f0.x = (h16)fr[0]; f0.y = (h16)fr[0];
    v2h f1; f1.x = (h16)fr[1]; f1.y = (h16)fr[1];
    const int m0 = mp * 2;   // chunk-local m
#pragma unroll
    for (int ch8 = 0; ch8 < 2; ++ch8) {
#pragma unroll
      for (int p = 0; p < 4; ++p) {
        v2h e0 = buf[ch8].p[p]     + f0 * (buf[2 + ch8].p[p] - buf[ch8].p[p]);
        v2h e1 = buf[4 + ch8].p[p] + f1 * (buf[6 + ch8].p[p] - buf[4 + ch8].p[p]);
        const int c = cg * 16 + ch8 * 8 + p * 2;
        v2h w0; w0.x = e0.x; w0.y = e1.x;
        v2h w1; w1.x = e0.y; w1.y = e1.y;
        *(v2h*)&E32[c * 40 + m0]       = w0;
        *(v2h*)&E32[(c + 1) * 40 + m0] = w1;
      }
    }
    v8h ra = *(const v8h*)&Rl[rrow * 136 + ks * 32 + g4 * 8];
    if (c15 >= 10) ra = vzero;
#pragma unroll
    for (int nt = 0; nt < 4; ++nt) {
      v8h bf = *(const v8h*)&E32[(nt * 16 + c15) * 40 + g4 * 8];
      tac[nt] = __builtin_amdgcn_mfma_f32_16x16x32_f16(ra, bf, tac[nt], 0, 0, 0);
    }
  };

  // 2-deep pipeline over the 4 chunks
  U8 bA[8], bB[8];
  float frA[2], frB[2];
  issue(0, bA, frA);
  issue(1, bB, frB);
  proc(0, bA, frA);
  issue(2, bA, frA);
  proc(1, bB, frB);
  issue(3, bB, frB);
  proc(2, bA, frA);
  proc(3, bB, frB);

  // ---- Vt: V[x][col] = T rows (x<10; 10..15 are genuine zeros from tac) ----
  h16* Vt = E32;   // reuse (same-wave lifetime: E32 fully consumed above)
  h16* Ul = Rl;
#pragma unroll
  for (int nt = 0; nt < 4; ++nt) {
    const int col = nt * 16 + c15;
    float tb = (g4 == 0) ? Tbias[col] : 0.0f;
    v4h pk;
    pk[0] = (h16)(tac[nt][0] * 0.05f + tb);
    pk[1] = (h16)(tac[nt][1] * 0.05f);
    pk[2] = (h16)(tac[nt][2] * 0.05f);
    pk[3] = (h16)(tac[nt][3] * 0.05f);
    *(v4h*)&Vt[col * 40 + g4 * 4] = pk;
  }
  // zero pad x = 16..31 (col = lane covers all 64 columns)
  *(v8h*)&Vt[lane * 40 + 16] = vzero;
  *(v8h*)&Vt[lane * 40 + 24] = vzero;

  // ---- U rows (16 lanes; a = lane): quadratic G2 terms, scaled by 1/16 ----
  if (lane < 16) {
    const h16* va = &Vt[lane * 40];
    const h16* vb = &Vt[(16 + lane) * 40];
    v8h Ta = *(const v8h*)va;
    v8h Tb = *(const v8h*)vb;
    v2h Tb8 = *(const v2h*)(vb + 8);
    float g1x = (float)Tb[1], g1y = (float)Tb[2], g1z = (float)Tb[3];
    v8h up;
    up[0] = (h16)((float)Ta[0] * USCL);
    up[1] = (h16)((float)Ta[1] * USCL);
    up[2] = (h16)((float)Ta[2] * USCL);
    up[3] = (h16)((float)Ta[3] * USCL);
    up[4] = (h16)((g1x * g1x + (float)Tb[4]) * USCL);
    up[5] = (h16)((g1y * g1y + (float)Tb[5]) * USCL);
    up[6] = (h16)((g1z * g1z + (float)Tb[6]) * USCL);
    up[7] = (h16)((1.4142135f * g1x * g1y + (float)Tb[7]) * USCL);
    *(v8h*)&Ul[lane * 40] = up;
    v2h u89;
    u89.x = (h16)((1.4142135f * g1y * g1z + (float)Tb8[0]) * USCL);
    u89.y = (h16)((1.4142135f * g1z * g1x + (float)Tb8[1]) * USCL);
    *(v2h*)&Ul[lane * 40 + 8] = u89;
    v2h z2 = {};
    v4h z4 = {};
    *(v2h*)&Ul[lane * 40 + 10] = z2;
    *(v4h*)&Ul[lane * 40 + 12] = z4;
    *(v8h*)&Ul[lane * 40 + 16] = vzero;
    *(v8h*)&Ul[lane * 40 + 24] = vzero;
  }

  // ---- G = U^T V via 4 MFMAs; store Gflat fp16/64 ----
  {
    v8h ua = *(const v8h*)&Ul[c15 * 40 + g4 * 8];
    h16* gp = Gout + (size_t)n * 1024;
#pragma unroll
    for (int nt = 0; nt < 4; ++nt) {
      v8h vb = *(const v8h*)&Vt[(nt * 16 + c15) * 40 + g4 * 8];
      f4 z = (f4){0.f, 0.f, 0.f, 0.f};
      f4 g = __builtin_amdgcn_mfma_f32_16x16x32_f16(ua, vb, z, 0, 0, 0);
#pragma unroll
      for (int r = 0; r < 4; ++r) {
        const int a = g4 * 4 + r;
        gp[a * 64 + nt * 16 + c15] = (h16)(g[r] * GOUTS);
      }
    }
  }
}

// ---------------------------------------------------------------------------
// Fused fit (unchanged from round 12).
// ---------------------------------------------------------------------------
__global__ __launch_bounds__(256) void k_fit(
    const h16* __restrict__ G16, const h16* __restrict__ W0t,
    const h16* __restrict__ W1t,
    const float* __restrict__ fb0, const float* __restrict__ fb1,
    const float* __restrict__ fW2, const float* __restrict__ fb2,
    const float* __restrict__ Ebias, float* __restrict__ BP)
{
  __shared__ h16 As[2][32][64]  __attribute__((aligned(16)));
  __shared__ h16 Bs[2][128][64] __attribute__((aligned(16)));
  __shared__ h16 ht[32][128]    __attribute__((aligned(16)));
  __shared__ h16 W1s[128][128]  __attribute__((aligned(16)));
  __shared__ float red[32][33];

  const int tid = threadIdx.x;
  const int abase = blockIdx.x * 32;
  const int t = (abase >= HALF_N) ? 1 : 0;
  const int lane = tid & 63, w = tid >> 6;
  const int c15 = lane & 15, g4 = lane >> 4;
  const int rt = w & 1, ng = w >> 1;

  float fb0v[4], b1v[4], w2v[4];
#pragma unroll
  for (int nt = 0; nt < 4; ++nt) {
    const int nn = ng * 64 + nt * 16 + c15;
    fb0v[nt] = K2 * fb0[t * 128 + nn];
    b1v[nt]  = K2 * fb1[t * 128 + nn];
    w2v[nt]  = fW2[t * 128 + nn];
  }

#pragma unroll
  for (int u = 0; u < 8; ++u) {
    int idx = u * 256 + tid;
    int nrow = idx >> 4, c8 = idx & 15;
    v8h v = *(const v8h*)&W1t[((size_t)t * 128 + nrow) * 128 + c8 * 8];
    int byte = nrow * 256 + ((c8 * 16) ^ ((nrow & 7) << 4));
    *(v8h*)((char*)&W1s[0][0] + byte) = v;
  }

  f4 acc[4];
#pragma unroll
  for (int nt = 0; nt < 4; ++nt) acc[nt] = (f4){0.f, 0.f, 0.f, 0.f};

  auto stageK = [&](int kc, int p) {
    {
      int r = tid >> 3, c8 = tid & 7;
      v8h v = *(const v8h*)&G16[(size_t)(abase + r) * 1024 + kc * 64 + c8 * 8];
      int byte = r * 128 + ((c8 * 16) ^ ((r & 7) << 4));
      *(v8h*)((char*)&As[p][0][0] + byte) = v;
    }
#pragma unroll
    for (int u = 0; u < 4; ++u) {
      int idx = u * 256 + tid;
      int nrow = idx >> 3, c8 = idx & 7;
      v8h v = *(const v8h*)&W0t[((size_t)t * 128 + nrow) * 1024 + kc * 64 + c8 * 8];
      int byte = nrow * 128 + ((c8 * 16) ^ ((nrow & 7) << 4));
      *(v8h*)((char*)&Bs[p][0][0] + byte) = v;
    }
  };

  stageK(0, 0);
  __syncthreads();
  for (int kc = 0; kc < 16; ++kc) {
    const int p = kc & 1;
    if (kc < 15) stageK(kc + 1, p ^ 1);
#pragma unroll
    for (int ksub = 0; ksub < 2; ++ksub) {
      const int ar = rt * 16 + c15;
      const int koff = (ksub * 32 + g4 * 8) * 2;
      v8h a = lds_v8h(&As[p][0][0], ar * 128 + (koff ^ ((ar & 7) << 4)));
#pragma unroll
      for (int nt = 0; nt < 4; ++nt) {
        const int br = ng * 64 + nt * 16 + c15;
        v8h b = lds_v8h(&Bs[p][0][0], br * 128 + (koff ^ ((br & 7) << 4)));
        acc[nt] = __builtin_amdgcn_mfma_f32_16x16x32_f16(a, b, acc[nt], 0, 0, 0);
      }
    }
    __syncthreads();
  }

#pragma unroll
  for (int nt = 0; nt < 4; ++nt)
#pragma unroll
    for (int r = 0; r < 4; ++r) {
      int a = rt * 16 + g4 * 4 + r;
      int k = ng * 64 + nt * 16 + c15;
      h16 hv = (h16)tanh_e2(acc[nt][r] + fb0v[nt]);
      int byte = a * 256 + ((k * 2) ^ ((a & 7) << 4));
      *((h16*)((char*)&ht[0][0] + byte)) = hv;
    }
  __syncthreads();

  f4 acc2[4];
#pragma unroll
  for (int nt = 0; nt < 4; ++nt) acc2[nt] = (f4){0.f, 0.f, 0.f, 0.f};
#pragma unroll
  for (int ks2 = 0; ks2 < 4; ++ks2) {
    const int ar = rt * 16 + c15;
    const int koff = (ks2 * 32 + g4 * 8) * 2;
    v8h a = lds_v8h(&ht[0][0], ar * 256 + (koff ^ ((ar & 7) << 4)));
#pragma unroll
    for (int nt = 0; nt < 4; ++nt) {
      const int br = ng * 64 + nt * 16 + c15;
      v8h b = lds_v8h(&W1s[0][0], br * 256 + (koff ^ ((br & 7) << 4)));
      acc2[nt] = __builtin_amdgcn_mfma_f32_16x16x32_f16(a, b, acc2[nt], 0, 0, 0);
    }
  }

#pragma unroll
  for (int r = 0; r < 4; ++r) {
    float v = 0.0f;
#pragma unroll
    for (int nt = 0; nt < 4; ++nt)
      v += tanh_e2(acc2[nt][r] + b1v[nt]) * w2v[nt];
    red[rt * 16 + g4 * 4 + r][ng * 16 + c15] = v;
  }
  __syncthreads();
  if (tid < 64) {
    const int a = tid & 31, half = tid >> 5;
    float s = 0.0f;
#pragma unroll
    for (int c = 0; c < 16; ++c) s += red[a][half * 16 + c];
    s += __shfl_xor(s, 32);
    s += __shfl_xor(s, 16);
    s += __shfl_xor(s, 8);
    s += __shfl_xor(s, 4);
    s += __shfl_xor(s, 2);
    s += __shfl_xor(s, 1);
    if (tid == 0) BP[blockIdx.x] = s + 32.0f * (fb2[t] + Ebias[t]);
  }
}

__global__ __launch_bounds__(64) void k_reduce(const float* __restrict__ BP,
                                               float* __restrict__ out)
{
  int tid = threadIdx.x;
  float s = BP[tid] + BP[tid + 64];
  s += __shfl_xor(s, 32);
  s += __shfl_xor(s, 16);
  s += __shfl_xor(s, 8);
  s += __shfl_xor(s, 4);
  s += __shfl_xor(s, 2);
  s += __shfl_xor(s, 1);
  if (tid == 0) out[0] = s;
}

extern "C" void kernel_launch(void* const* d_in, const int* in_sizes, int n_in,
                              void* d_out, int out_size, void* d_ws, size_t ws_size,
                              hipStream_t stream) {
  const float* coord = (const float*)d_in[0];
  const float* box   = (const float*)d_in[1];
  const int*   nbrs  = (const int*)d_in[2];
  const float* eW0   = (const float*)d_in[3];
  const float* eb0   = (const float*)d_in[4];
  const float* eW1   = (const float*)d_in[5];
  const float* eb1   = (const float*)d_in[6];
  const float* eW2   = (const float*)d_in[7];
  const float* eb2   = (const float*)d_in[8];
  const float* Tbias = (const float*)d_in[9];
  const float* fW0   = (const float*)d_in[10];
  const float* fb0   = (const float*)d_in[11];
  const float* fW1   = (const float*)d_in[12];
  const float* fb1   = (const float*)d_in[13];
  const float* fW2   = (const float*)d_in[14];
  const float* fb2   = (const float*)d_in[15];
  const float* Ebias = (const float*)d_in[16];

  char* ws = (char*)d_ws;
  h16*   G16 = (h16*)ws;                                   // 8 MB
  h16*   W0t = (h16*)(ws + (size_t)8  * 1024 * 1024);      // 512 KB
  h16*   W1t = (h16*)(ws + (size_t)9  * 1024 * 1024);      // 64 KB
  h16*   tbl = (h16*)(ws + (size_t)10 * 1024 * 1024);      // 1 MB
  f4*    cP  = (f4*)(ws + (size_t)11 * 1024 * 1024);       // 64 KB
  float* BP  = (float*)(ws + (size_t)12 * 1024 * 1024);    // 512 B

  k_setup<<<672, 256, 0, stream>>>(eW0, eb0, eW1, eb1, eW2, eb2, fW0, fW1,
                                   coord, tbl, W0t, W1t, cP);
  // MEASUREMENT: k_embed is idempotent (reads setup outputs, writes only G16).
  // 11 launches -> T_embed = (dur_us - 42.7)/10.
  for (int rep = 0; rep < 11; ++rep)
    k_embed<<<1024, 256, 0, stream>>>(cP, box, nbrs, Tbias, tbl, G16);
  k_fit<<<128, 256, 0, stream>>>(G16, W0t, W1t, fb0, fb1, fW2, fb2, Ebias, BP);
  k_reduce<<<1, 64, 0, stream>>>(BP, (float*)d_out);
}

// Round 14
// 45.462 us; speedup vs baseline: 3.2951x; 3.2951x over previous
//
#include <hip/hip_runtime.h>
#include <hip/hip_fp16.h>

typedef _Float16 h16;
typedef h16 v2h __attribute__((ext_vector_type(2)));
typedef h16 v4h __attribute__((ext_vector_type(4)));
typedef h16 v8h __attribute__((ext_vector_type(8)));
typedef float f4 __attribute__((ext_vector_type(4)));

#define NATOM 4096
#define HALF_N 2048
#define K2 2.885390081777927f      // 2/ln2: tanh(x) = 1 - 2/(1+exp2(K2*x))
#define GSCL 0.015625f             // G stored as fp16 * 1/64
#define W0SCL (64.0f * K2)         // W0t staged as fp16 * 64 * K2
#define USCL 0.0625f               // U rows stored /16 (fp16 headroom)
#define GOUTS (GSCL / USCL)        // 0.25

#define TBL_N 2048
#define W0MIN_ (-0.201f)
#define DW_ (1.2005f / 2047.0f)
#define RSCALE_ (2047.0f / 1.2005f)

__device__ __forceinline__ float rcp_fast(float x) {
#if __has_builtin(__builtin_amdgcn_rcpf)
  return __builtin_amdgcn_rcpf(x);
#else
  return 1.0f / x;
#endif
}

__device__ __forceinline__ float exp2_fast(float x) {
#if __has_builtin(__builtin_amdgcn_exp2f)
  return __builtin_amdgcn_exp2f(x);
#else
  return exp2f(x);
#endif
}

__device__ __forceinline__ float tanh_e2(float d) {
  float r = rcp_fast(1.0f + exp2_fast(d));
  return fmaf(-2.0f, r, 1.0f);
}

__device__ __forceinline__ v8h lds_v8h(const h16* base, int byte) {
  return *(const v8h*)((const char*)base + byte);
}

// ---------------------------------------------------------------------------
// Setup. Blocks 0..511: embedding table (sW1 staged TRANSPOSED -> uniform
// b128 broadcast reads instead of 512 per-lane b32). 512..639: fW0 -> W0t.
// 640..655: coord float4 pack (+ block 640 zeroes the fit counter).
// 656..671: fW1 -> W1t.
// ---------------------------------------------------------------------------
__global__ __launch_bounds__(256) void k_setup(
    const float* __restrict__ eW0, const float* __restrict__ eb0,
    const float* __restrict__ eW1, const float* __restrict__ eb1,
    const float* __restrict__ eW2, const float* __restrict__ eb2,
    const float* __restrict__ fW0, const float* __restrict__ fW1,
    const float* __restrict__ coord,
    h16* __restrict__ tbl, h16* __restrict__ W0t, h16* __restrict__ W1t,
    f4* __restrict__ coordP, int* __restrict__ counter)
{
  const int bid = blockIdx.x, tid = threadIdx.x;
  if (bid < 512) {
    __shared__ float sW1t[32][16];   // transposed: [j][i]
    __shared__ float sW2[2048];
    __shared__ float sW0s[16], sb0s[16], sb1s[32], sb2s[64];
    const int net = bid >> 7;
    for (int i = tid; i < 512; i += 256) {
      int j = i >> 4, ii = i & 15;
      sW1t[j][ii] = eW1[net * 512 + ii * 32 + j];
    }
    for (int i = tid; i < 2048; i += 256) sW2[i] = eW2[net * 2048 + i];
    if (tid < 16) { sW0s[tid] = eW0[net * 16 + tid]; sb0s[tid] = eb0[net * 16 + tid]; }
    else if (tid >= 32 && tid < 64) sb1s[tid - 32] = eb1[net * 32 + tid - 32];
    else if (tid >= 64 && tid < 128) sb2s[tid - 64] = eb2[net * 64 + tid - 64];
    __syncthreads();

    const int u = (bid & 127) * 256 + tid;     // 0..32767
    const int e = u >> 4, cq = u & 15;
    const float w = W0MIN_ + (float)e * DW_;
    const float s = 8.0f * w * rcp_fast(1.0f - fabsf(w));
    float h0[16];
#pragma unroll
    for (int i = 0; i < 16; ++i)
      h0[i] = tanh_e2(K2 * fmaf(s, sW0s[i], sb0s[i]));
    f4 h04[4];
#pragma unroll
    for (int q = 0; q < 4; ++q) {
      h04[q].x = h0[q * 4]; h04[q].y = h0[q * 4 + 1];
      h04[q].z = h0[q * 4 + 2]; h04[q].w = h0[q * 4 + 3];
    }
    float h1[32];
#pragma unroll
    for (int j = 0; j < 32; ++j) {
      f4 p = h04[0] * (*(const f4*)&sW1t[j][0]);
      p += h04[1] * (*(const f4*)&sW1t[j][4]);
      p += h04[2] * (*(const f4*)&sW1t[j][8]);
      p += h04[3] * (*(const f4*)&sW1t[j][12]);
      float a = sb1s[j] + (p.x + p.y) + (p.z + p.w);
      h1[j] = tanh_e2(K2 * a);
    }
    f4 a4 = *(const f4*)&sb2s[cq * 4];
    for (int j = 0; j < 32; ++j) {
      f4 wv4 = *(const f4*)&sW2[j * 64 + cq * 4];
      a4 += h1[j] * wv4;
    }
    union { h16 e4[4]; unsigned long long q; } o;
#pragma unroll
    for (int q = 0; q < 4; ++q) o.e4[q] = (h16)tanh_e2(K2 * a4[q]);
    *(unsigned long long*)&tbl[((size_t)(net * TBL_N + e)) * 64 + cq * 4] = o.q;
  } else if (bid < 640) {
    int idx = (bid - 512) * 256 + tid;          // 0..32767
    int t = idx >> 14, n = idx & 127, k8 = (idx >> 7) & 127;
    union { v8h v; h16 e[8]; } o;
#pragma unroll
    for (int i = 0; i < 8; ++i)
      o.e[i] = (h16)(W0SCL * fW0[(size_t)t * 131072 + (size_t)(k8 * 8 + i) * 128 + n]);
    *(v8h*)&W0t[((size_t)t * 128 + n) * 1024 + k8 * 8] = o.v;
  } else if (bid < 656) {
    if (bid == 640 && tid == 0) *counter = 0;   // zero fit's last-block counter
    int idx = (bid - 640) * 256 + tid;          // 0..4095
    f4 c;
    c.x = coord[idx]; c.y = coord[NATOM + idx]; c.z = coord[2 * NATOM + idx];
    c.w = 0.0f;
    coordP[idx] = c;
  } else {
    int idx = (bid - 656) * 256 + tid;          // 0..4095
    int t = idx >> 11, rem = idx & 2047;
    int n = rem >> 4, k8 = rem & 15;
    union { v8h v; h16 e[8]; } o;
#pragma unroll
    for (int i = 0; i < 8; ++i)
      o.e[i] = (h16)(K2 * fW1[(size_t)t * 16384 + (size_t)(k8 * 8 + i) * 128 + n]);
    *(v8h*)&W1t[((size_t)t * 128 + n) * 128 + k8 * 8] = o.v;
  }
}

// ---------------------------------------------------------------------------
// Kernel 1 (unchanged from round 12; measured ~10.7 us incl launch).
// ---------------------------------------------------------------------------
__global__ __launch_bounds__(256, 4) void k_embed(
    const f4* __restrict__ coordP, const float* __restrict__ box,
    const int* __restrict__ nbrs, const float* __restrict__ Tbias,
    const h16* __restrict__ tbl, h16* __restrict__ Gout)
{
  __shared__ h16 pool1[4][2560] __attribute__((aligned(16)));
  __shared__ h16 pool2[4][1360] __attribute__((aligned(16)));

  const int tid = threadIdx.x;
  const int wv = tid >> 6;
  const int lane = tid & 63;
  const int n = blockIdx.x * 4 + wv;
  const int ti = (n >= HALF_N) ? 1 : 0;
  const int c15 = lane & 15, g4 = lane >> 4;
  const int mp = lane >> 2, cg = lane & 3;

  h16* E32 = &pool1[wv][0];
  h16* Rl  = &pool2[wv][0];

  const int jnb0 = nbrs[(size_t)n * 128 + lane];
  const int jnb1 = nbrs[(size_t)n * 128 + 64 + lane];

  int uf0 = 0, uf1 = 0;
  {
    const float bx = box[0], by = box[1], bz = box[2];
    const float rbx = rcp_fast(bx), rby = rcp_fast(by), rbz = rcp_fast(bz);
    const f4 cme = coordP[n];
#pragma unroll
    for (int nb = 0; nb < 2; ++nb) {
      const int m = nb * 64 + lane;
      const f4 cj = coordP[nb ? jnb1 : jnb0];
      float dx = cj.x - cme.x;
      float dy = cj.y - cme.y;
      float dz = cj.z - cme.z;
      dx -= bx * rintf(dx * rbx);
      dy -= by * rintf(dy * rby);
      dz -= bz * rintf(dz * rbz);
      float r2 = dx * dx + dy * dy + dz * dz;
      bool mk = r2 > 1e-12f;
      float rs = sqrtf(mk ? r2 : 1.0f);
      float r  = mk ? rs : 0.0f;
      float sw = 0.5f * __cosf(0.52359878f * fminf(r, 6.0f)) + 0.5f;
      float invr = mk ? rcp_fast(rs) : 1.0f;
      float sr = (mk && r < 6.0f) ? sw * invr : 0.0f;
      float x0 = dx * invr, x1 = dy * invr, x2 = dz * invr;
      float srn = sr * 20.0f;
      float s   = (sr - 0.1f) * 20.0f;
      Rl[0 * 136 + m] = (h16)srn;
      Rl[1 * 136 + m] = (h16)(1.7320508f * srn * x0);
      Rl[2 * 136 + m] = (h16)(1.7320508f * srn * x1);
      Rl[3 * 136 + m] = (h16)(1.7320508f * srn * x2);
      Rl[4 * 136 + m] = (h16)(3.0f * srn * (x0 * x0 - 0.33333334f));
      Rl[5 * 136 + m] = (h16)(3.0f * srn * (x1 * x1 - 0.33333334f));
      Rl[6 * 136 + m] = (h16)(3.0f * srn * (x2 * x2 - 0.33333334f));
      Rl[7 * 136 + m] = (h16)(4.2426407f * srn * (x0 * x1));
      Rl[8 * 136 + m] = (h16)(4.2426407f * srn * (x1 * x2));
      Rl[9 * 136 + m] = (h16)(4.2426407f * srn * (x2 * x0));
      float wr = s * rcp_fast(8.0f + fabsf(s));
      float fidx = (wr - W0MIN_) * RSCALE_;
      fidx = fminf(fmaxf(fidx, 0.0f), 2045.99f);
      float i0f = floorf(fidx);
      h16 frh = (h16)(fidx - i0f);
      int uf = ((int)i0f << 16) |
               (int)__builtin_bit_cast(unsigned short, frh);
      if (nb == 0) uf0 = uf; else uf1 = uf;
    }
  }

  union U8 { v8h v; v2h p[4]; h16 e[8]; };
  const int rrow = (c15 < 10) ? c15 : 9;
  const v8h vzero = {};
  f4 tac[4];
#pragma unroll
  for (int nt = 0; nt < 4; ++nt) tac[nt] = (f4){0.f, 0.f, 0.f, 0.f};

  auto issue = [&](int ks, U8* buf, float* fr) {
#pragma unroll
    for (int e = 0; e < 2; ++e) {
      int src = ((ks & 1) * 32 + mp * 2 + e) * 4;
      unsigned uu = (unsigned)__builtin_amdgcn_ds_bpermute(src, (ks < 2) ? uf0 : uf1);
      int i0 = (int)(uu >> 16);
      fr[e] = (float)__builtin_bit_cast(h16, (unsigned short)(uu & 0xffffu));
      const int net = ti * 2 + (ks >> 1);
      const h16* rp = tbl + ((size_t)net * TBL_N + i0) * 64 + cg * 16;
      buf[e * 4 + 0].v = *(const v8h*)(rp);
      buf[e * 4 + 1].v = *(const v8h*)(rp + 8);
      buf[e * 4 + 2].v = *(const v8h*)(rp + 64);
      buf[e * 4 + 3].v = *(const v8h*)(rp + 72);
    }
  };

  auto proc = [&](int ks, U8* buf, const float* fr) {
    v2h f0; f0.x = (h16)fr[0]; f0.y = (h16)fr[0];
    v2h f1; f1.x = (h16)fr[1]; f1.y = (h16)fr[1];
    const int m0 = mp * 2;
#pragma unroll
    for (int ch8 = 0; ch8 < 2; ++ch8) {
#pragma unroll
      for (int p = 0; p < 4; ++p) {
        v2h e0 = buf[ch8].p[p]     + f0 * (buf[2 + ch8].p[p] - buf[ch8].p[p]);
        v2h e1 = buf[4 + ch8].p[p] + f1 * (buf[6 + ch8].p[p] - buf[4 + ch8].p[p]);
        const int c = cg * 16 + ch8 * 8 + p * 2;
        v2h w0; w0.x = e0.x; w0.y = e1.x;
        v2h w1; w1.x = e0.y; w1.y = e1.y;
        *(v2h*)&E32[c * 40 + m0]       = w0;
        *(v2h*)&E32[(c + 1) * 40 + m0] = w1;
      }
    }
    v8h ra = *(const v8h*)&Rl[rrow * 136 + ks * 32 + g4 * 8];
    if (c15 >= 10) ra = vzero;
#pragma unroll
    for (int nt = 0; nt < 4; ++nt) {
      v8h bf = *(const v8h*)&E32[(nt * 16 + c15) * 40 + g4 * 8];
      tac[nt] = __builtin_amdgcn_mfma_f32_16x16x32_f16(ra, bf, tac[nt], 0, 0, 0);
    }
  };

  U8 bA[8], bB[8];
  float frA[2], frB[2];
  issue(0, bA, frA);
  issue(1, bB, frB);
  proc(0, bA, frA);
  issue(2, bA, frA);
  proc(1, bB, frB);
  issue(3, bB, frB);
  proc(2, bA, frA);
  proc(3, bB, frB);

  h16* Vt = E32;
  h16* Ul = Rl;
#pragma unroll
  for (int nt = 0; nt < 4; ++nt) {
    const int col = nt * 16 + c15;
    float tb = (g4 == 0) ? Tbias[col] : 0.0f;
    v4h pk;
    pk[0] = (h16)(tac[nt][0] * 0.05f + tb);
    pk[1] = (h16)(tac[nt][1] * 0.05f);
    pk[2] = (h16)(tac[nt][2] * 0.05f);
    pk[3] = (h16)(tac[nt][3] * 0.05f);
    *(v4h*)&Vt[col * 40 + g4 * 4] = pk;
  }
  *(v8h*)&Vt[lane * 40 + 16] = vzero;
  *(v8h*)&Vt[lane * 40 + 24] = vzero;

  if (lane < 16) {
    const h16* va = &Vt[lane * 40];
    const h16* vb = &Vt[(16 + lane) * 40];
    v8h Ta = *(const v8h*)va;
    v8h Tb = *(const v8h*)vb;
    v2h Tb8 = *(const v2h*)(vb + 8);
    float g1x = (float)Tb[1], g1y = (float)Tb[2], g1z = (float)Tb[3];
    v8h up;
    up[0] = (h16)((float)Ta[0] * USCL);
    up[1] = (h16)((float)Ta[1] * USCL);
    up[2] = (h16)((float)Ta[2] * USCL);
    up[3] = (h16)((float)Ta[3] * USCL);
    up[4] = (h16)((g1x * g1x + (float)Tb[4]) * USCL);
    up[5] = (h16)((g1y * g1y + (float)Tb[5]) * USCL);
    up[6] = (h16)((g1z * g1z + (float)Tb[6]) * USCL);
    up[7] = (h16)((1.4142135f * g1x * g1y + (float)Tb[7]) * USCL);
    *(v8h*)&Ul[lane * 40] = up;
    v2h u89;
    u89.x = (h16)((1.4142135f * g1y * g1z + (float)Tb8[0]) * USCL);
    u89.y = (h16)((1.4142135f * g1z * g1x + (float)Tb8[1]) * USCL);
    *(v2h*)&Ul[lane * 40 + 8] = u89;
    v2h z2 = {};
    v4h z4 = {};
    *(v2h*)&Ul[lane * 40 + 10] = z2;
    *(v4h*)&Ul[lane * 40 + 12] = z4;
    *(v8h*)&Ul[lane * 40 + 16] = vzero;
    *(v8h*)&Ul[lane * 40 + 24] = vzero;
  }

  {
    v8h ua = *(const v8h*)&Ul[c15 * 40 + g4 * 8];
    h16* gp = Gout + (size_t)n * 1024;
#pragma unroll
    for (int nt = 0; nt < 4; ++nt) {
      v8h vb = *(const v8h*)&Vt[(nt * 16 + c15) * 40 + g4 * 8];
      f4 z = (f4){0.f, 0.f, 0.f, 0.f};
      f4 g = __builtin_amdgcn_mfma_f32_16x16x32_f16(ua, vb, z, 0, 0, 0);
#pragma unroll
      for (int r = 0; r < 4; ++r) {
        const int a = g4 * 4 + r;
        gp[a * 64 + nt * 16 + c15] = (h16)(g[r] * GOUTS);
      }
    }
  }
}

// ---------------------------------------------------------------------------
// Fused fit + final reduce: 256 blocks x 16 atoms (all CUs), K-step 128
// (8 double-buffered steps), pooled 72KB LDS -> 2 blocks/CU. Last block
// (device-scope counter) reduces BP deterministically into out.
// ---------------------------------------------------------------------------
__global__ __launch_bounds__(256, 2) void k_fit(
    const h16* __restrict__ G16, const h16* __restrict__ W0t,
    const h16* __restrict__ W1t,
    const float* __restrict__ fb0, const float* __restrict__ fb1,
    const float* __restrict__ fW2, const float* __restrict__ fb2,
    const float* __restrict__ Ebias,
    float* __restrict__ BP, int* __restrict__ counter,
    float* __restrict__ out)
{
  // pool layout (bytes):
  //   L0 phase: As[p] = p*36864 + [0,4096);  Bs[p] = p*36864 + [4096,36864)
  //   L1 phase: ht = [0,4096); W1s = [4096,36864); red = [40960,45056)
  __shared__ h16 pool[36864] __attribute__((aligned(16)));
  __shared__ int lastFlag;
  const int tid = threadIdx.x;
  const int abase = blockIdx.x * 16;
  const int t = (abase >= HALF_N) ? 1 : 0;
  const int lane = tid & 63, w = tid >> 6;
  const int c15 = lane & 15, g4 = lane >> 4;

  float fb0v[2], b1v[2], w2v[2];
#pragma unroll
  for (int nt = 0; nt < 2; ++nt) {
    const int nn = w * 32 + nt * 16 + c15;
    fb0v[nt] = K2 * fb0[t * 128 + nn];
    b1v[nt]  = K2 * fb1[t * 128 + nn];
    w2v[nt]  = fW2[t * 128 + nn];
  }

  auto stageK = [&](int kc, int p) {
    {
      int r = tid >> 4, c8 = tid & 15;
      v8h v = *(const v8h*)&G16[(size_t)(abase + r) * 1024 + kc * 128 + c8 * 8];
      int byte = p * 36864 + r * 256 + ((c8 * 16) ^ ((r & 7) << 4));
      *(v8h*)((char*)pool + byte) = v;
    }
#pragma unroll
    for (int u = 0; u < 8; ++u) {
      int idx = u * 256 + tid;
      int nr = idx >> 4, c8 = idx & 15;
      v8h v = *(const v8h*)&W0t[((size_t)t * 128 + nr) * 1024 + kc * 128 + c8 * 8];
      int byte = p * 36864 + 4096 + nr * 256 + ((c8 * 16) ^ ((nr & 7) << 4));
      *(v8h*)((char*)pool + byte) = v;
    }
  };

  f4 acc[2];
  acc[0] = (f4){0.f, 0.f, 0.f, 0.f};
  acc[1] = (f4){0.f, 0.f, 0.f, 0.f};

  stageK(0, 0);
  __syncthreads();
  for (int kc = 0; kc < 8; ++kc) {
    const int p = kc & 1;
    if (kc < 7) stageK(kc + 1, p ^ 1);
#pragma unroll
    for (int ksub = 0; ksub < 4; ++ksub) {
      const int koff = (ksub * 32 + g4 * 8) * 2;
      v8h a = lds_v8h(pool, p * 36864 + c15 * 256 + (koff ^ ((c15 & 7) << 4)));
#pragma unroll
      for (int nt = 0; nt < 2; ++nt) {
        const int br = w * 32 + nt * 16 + c15;
        v8h b = lds_v8h(pool,
                        p * 36864 + 4096 + br * 256 + (koff ^ ((br & 7) << 4)));
        acc[nt] = __builtin_amdgcn_mfma_f32_16x16x32_f16(a, b, acc[nt], 0, 0, 0);
      }
    }
    __syncthreads();
  }

  // ht (bytes [0,4096), overlaps dead As[0]) + W1s (bytes [4096,36864),
  // overlaps dead Bs[0]); safe: last K-step read only buffer p=1.
#pragma unroll
  for (int nt = 0; nt < 2; ++nt)
#pragma unroll
    for (int r = 0; r < 4; ++r) {
      int a = g4 * 4 + r;                  // atom 0..15
      int col = w * 32 + nt * 16 + c15;    // 0..127
      h16 hv = (h16)tanh_e2(acc[nt][r] + fb0v[nt]);
      int byte = a * 256 + ((col * 2) ^ ((a & 7) << 4));
      *((h16*)((char*)pool + byte)) = hv;
    }
#pragma unroll
  for (int u = 0; u < 8; ++u) {
    int idx = u * 256 + tid;
    int nr = idx >> 4, c8 = idx & 15;
    v8h v = *(const v8h*)&W1t[((size_t)t * 128 + nr) * 128 + c8 * 8];
    int byte = 4096 + nr * 256 + ((c8 * 16) ^ ((nr & 7) << 4));
    *(v8h*)((char*)pool + byte) = v;
  }
  __syncthreads();

  // layer 1: h1 = h0 @ W1 via MFMA (K=128)
  f4 acc2[2];
  acc2[0] = (f4){0.f, 0.f, 0.f, 0.f};
  acc2[1] = (f4){0.f, 0.f, 0.f, 0.f};
#pragma unroll
  for (int ks2 = 0; ks2 < 4; ++ks2) {
    const int koff = (ks2 * 32 + g4 * 8) * 2;
    v8h a = lds_v8h(pool, c15 * 256 + (koff ^ ((c15 & 7) << 4)));
#pragma unroll
    for (int nt = 0; nt < 2; ++nt) {
      const int br = w * 32 + nt * 16 + c15;
      v8h b = lds_v8h(pool, 4096 + br * 256 + (koff ^ ((br & 7) << 4)));
      acc2[nt] = __builtin_amdgcn_mfma_f32_16x16x32_f16(a, b, acc2[nt], 0, 0, 0);
    }
  }

  // layer 2 + per-block partial
  float* redp = (float*)((char*)pool + 40960);   // [16][64]
#pragma unroll
  for (int r = 0; r < 4; ++r) {
    float v = 0.0f;
#pragma unroll
    for (int nt = 0; nt < 2; ++nt)
      v += tanh_e2(acc2[nt][r] + b1v[nt]) * w2v[nt];
    redp[(g4 * 4 + r) * 64 + w * 16 + c15] = v;
  }
  __syncthreads();
  if (tid < 64) {
    float s = 0.0f;
#pragma unroll
    for (int u = 0; u < 16; ++u) s += redp[tid + u * 64];
    s += __shfl_xor(s, 32);
    s += __shfl_xor(s, 16);
    s += __shfl_xor(s, 8);
    s += __shfl_xor(s, 4);
    s += __shfl_xor(s, 2);
    s += __shfl_xor(s, 1);
    if (tid == 0) {
      float blockSum = s + 16.0f * (fb2[t] + Ebias[t]);
      __hip_atomic_store(&BP[blockIdx.x], blockSum, __ATOMIC_RELEASE,
                         __HIP_MEMORY_SCOPE_AGENT);
      int old = __hip_atomic_fetch_add(counter, 1, __ATOMIC_ACQ_REL,
                                       __HIP_MEMORY_SCOPE_AGENT);
      lastFlag = (old == 255) ? 1 : 0;
    }
  }
  __syncthreads();
  if (lastFlag && tid < 64) {
    float s = 0.0f;
#pragma unroll
    for (int q = 0; q < 4; ++q)
      s += __hip_atomic_load(&BP[tid + q * 64], __ATOMIC_ACQUIRE,
                             __HIP_MEMORY_SCOPE_AGENT);
    s += __shfl_xor(s, 32);
    s += __shfl_xor(s, 16);
    s += __shfl_xor(s, 8);
    s += __shfl_xor(s, 4);
    s += __shfl_xor(s, 2);
    s += __shfl_xor(s, 1);
    if (tid == 0) out[0] = s;
  }
}

extern "C" void kernel_launch(void* const* d_in, const int* in_sizes, int n_in,
                              void* d_out, int out_size, void* d_ws, size_t ws_size,
                              hipStream_t stream) {
  const float* coord = (const float*)d_in[0];
  const float* box   = (const float*)d_in[1];
  const int*   nbrs  = (const int*)d_in[2];
  const float* eW0   = (const float*)d_in[3];
  const float* eb0   = (const float*)d_in[4];
  const float* eW1   = (const float*)d_in[5];
  const float* eb1   = (const float*)d_in[6];
  const float* eW2   = (const float*)d_in[7];
  const float* eb2   = (const float*)d_in[8];
  const float* Tbias = (const float*)d_in[9];
  const float* fW0   = (const float*)d_in[10];
  const float* fb0   = (const float*)d_in[11];
  const float* fW1   = (const float*)d_in[12];
  const float* fb1   = (const float*)d_in[13];
  const float* fW2   = (const float*)d_in[14];
  const float* fb2   = (const float*)d_in[15];
  const float* Ebias = (const float*)d_in[16];

  char* ws = (char*)d_ws;
  h16*   G16 = (h16*)ws;                                   // 8 MB
  h16*   W0t = (h16*)(ws + (size_t)8  * 1024 * 1024);      // 512 KB
  h16*   W1t = (h16*)(ws + (size_t)9  * 1024 * 1024);      // 64 KB
  h16*   tbl = (h16*)(ws + (size_t)10 * 1024 * 1024);      // 1 MB
  f4*    cP  = (f4*)(ws + (size_t)11 * 1024 * 1024);       // 64 KB
  float* BP  = (float*)(ws + (size_t)12 * 1024 * 1024);    // 1 KB
  int*   cnt = (int*)(ws + (size_t)12 * 1024 * 1024 + 4096);

  k_setup<<<672, 256, 0, stream>>>(eW0, eb0, eW1, eb1, eW2, eb2, fW0, fW1,
                                   coord, tbl, W0t, W1t, cP, cnt);
  k_embed<<<1024, 256, 0, stream>>>(cP, box, nbrs, Tbias, tbl, G16);
  k_fit<<<256, 256, 0, stream>>>(G16, W0t, W1t, fb0, fb1, fW2, fb2, Ebias,
                                 BP, cnt, (float*)d_out);
}